// Round 1
// baseline (1371.330 us; speedup 1.0000x reference)
//
#include <hip/hip_runtime.h>
#include <cmath>

#define T_TOK 8192
#define N_EXP 256
#define HID   7168
#define BM 64
#define BN 64
#define BK 32

// ---------------------------------------------------------------------------
// Kernel 1: fp64-accumulated router GEMM + sigmoid epilogue.
// x: [T, H] f32 row-major, w: [E, H] f32 row-major (both K-contiguous).
// scores[t*E + e] = sigmoid(dot(x[t], w[e])) as double, written to workspace.
// Tile 64x64 per 256-thread block, 4x4 micro-tile per thread, BK=32.
// fp64 accumulation so the top-k order matches a float64 numpy reference
// exactly (index threshold ~5 => effectively zero tolerance for rank flips).
// ---------------------------------------------------------------------------
__global__ __launch_bounds__(256)
void gemm_scores_f64(const float* __restrict__ x, const float* __restrict__ w,
                     double* __restrict__ scores)
{
    __shared__ float xs[BK][BM];
    __shared__ float wsh[BK][BN];
    const int tid = threadIdx.x;
    const int e0 = blockIdx.x * BN;
    const int t0 = blockIdx.y * BM;
    const int tx = tid & 15;   // expert sub-tile 0..15
    const int ty = tid >> 4;   // token  sub-tile 0..15

    double acc[4][4];
#pragma unroll
    for (int i = 0; i < 4; ++i)
#pragma unroll
        for (int j = 0; j < 4; ++j) acc[i][j] = 0.0;

    for (int k0 = 0; k0 < HID; k0 += BK) {
        // Stage x-tile and w-tile: 64 rows x 32 k each = 512 float4 per tile,
        // 2 float4 per thread per tile. Coalesced 64B row segments.
#pragma unroll
        for (int i = 0; i < 2; ++i) {
            const int fi = tid + i * 256;   // 0..511
            const int m  = fi >> 3;         // row 0..63
            const int kq = fi & 7;          // float4 within row
            const float4 xv = *(const float4*)(x + (size_t)(t0 + m) * HID + k0 + kq * 4);
            xs[kq * 4 + 0][m] = xv.x;
            xs[kq * 4 + 1][m] = xv.y;
            xs[kq * 4 + 2][m] = xv.z;
            xs[kq * 4 + 3][m] = xv.w;
            const float4 wv = *(const float4*)(w + (size_t)(e0 + m) * HID + k0 + kq * 4);
            wsh[kq * 4 + 0][m] = wv.x;
            wsh[kq * 4 + 1][m] = wv.y;
            wsh[kq * 4 + 2][m] = wv.z;
            wsh[kq * 4 + 3][m] = wv.w;
        }
        __syncthreads();
#pragma unroll
        for (int kk = 0; kk < BK; ++kk) {
            const float4 a4 = *(const float4*)&xs[kk][ty * 4];
            const float4 b4 = *(const float4*)&wsh[kk][tx * 4];
            const double a0 = (double)a4.x, a1 = (double)a4.y;
            const double a2 = (double)a4.z, a3 = (double)a4.w;
            const double b0 = (double)b4.x, b1 = (double)b4.y;
            const double b2 = (double)b4.z, b3 = (double)b4.w;
            acc[0][0] += a0 * b0; acc[0][1] += a0 * b1; acc[0][2] += a0 * b2; acc[0][3] += a0 * b3;
            acc[1][0] += a1 * b0; acc[1][1] += a1 * b1; acc[1][2] += a1 * b2; acc[1][3] += a1 * b3;
            acc[2][0] += a2 * b0; acc[2][1] += a2 * b1; acc[2][2] += a2 * b2; acc[2][3] += a2 * b3;
            acc[3][0] += a3 * b0; acc[3][1] += a3 * b1; acc[3][2] += a3 * b2; acc[3][3] += a3 * b3;
        }
        __syncthreads();
    }

#pragma unroll
    for (int i = 0; i < 4; ++i) {
        const int t = t0 + ty * 4 + i;
#pragma unroll
        for (int j = 0; j < 4; ++j) {
            const int e = e0 + tx * 4 + j;
            scores[(size_t)t * N_EXP + e] = 1.0 / (1.0 + exp(-acc[i][j]));
        }
    }
}

// ---------------------------------------------------------------------------
// Kernel 2: per-token routing, one thread per token, all in fp64.
// Exactly emulates: group top-2 sums -> top-4 groups (ties: lower index) ->
// top-8 over masked scores where masked-out experts contribute 0.0 (stable,
// equal values keep lower index) -> weights from sigmoid scores, normalized,
// scaled by 2.5. Indices written as float values.
// ---------------------------------------------------------------------------
__global__ __launch_bounds__(256)
void route_topk(const double* __restrict__ scores, const float* __restrict__ bias,
                float* __restrict__ out_idx, float* __restrict__ out_w)
{
    __shared__ double bs[N_EXP];
    const int tid = threadIdx.x;
    bs[tid] = (double)bias[tid];
    __syncthreads();

    const int t = blockIdx.x * 256 + tid;
    const double* s = scores + (size_t)t * N_EXP;

    // Per-group score = sum of top-2 (score + bias) in the group of 32.
    double gs[8];
#pragma unroll
    for (int g = 0; g < 8; ++g) {
        double m1 = -1e300, m2 = -1e300;
        for (int j = 0; j < 32; ++j) {
            const int e = g * 32 + j;
            const double v = s[e] + bs[e];
            if (v > m1) { m2 = m1; m1 = v; }
            else if (v > m2) { m2 = v; }
        }
        gs[g] = m1 + m2;
    }

    // Top-4 groups; strict > keeps the lowest index on ties (top_k semantics).
    int gm = 0;
    for (int r = 0; r < 4; ++r) {
        int best = 0; double bv = -1e300;
#pragma unroll
        for (int g = 0; g < 8; ++g) {
            const bool taken = (gm >> g) & 1;
            if (!taken && gs[g] > bv) { bv = gs[g]; best = g; }
        }
        gm |= (1 << best);
    }

    // Stable top-8 over masked scores (masked-out -> 0.0 candidate).
    double tv[8]; int ti[8];
#pragma unroll
    for (int i = 0; i < 8; ++i) { tv[i] = -1e300; ti[i] = 0; }
    for (int e = 0; e < N_EXP; ++e) {
        double cv = ((gm >> (e >> 5)) & 1) ? (s[e] + bs[e]) : 0.0;
        int ci = e;
#pragma unroll
        for (int p = 0; p < 8; ++p) {
            const bool sw = cv > tv[p];   // strict: equal keeps earlier (lower idx)
            const double od = tv[p]; const int oi = ti[p];
            if (sw) { tv[p] = cv; ti[p] = ci; cv = od; ci = oi; }
        }
    }

    // Weights come from the raw sigmoid scores (no bias) at chosen indices.
    double wv[8]; double wsum = 0.0;
#pragma unroll
    for (int i = 0; i < 8; ++i) { wv[i] = s[ti[i]]; wsum += wv[i]; }
    const double scale = 2.5 / (wsum + 1e-20);
#pragma unroll
    for (int i = 0; i < 8; ++i) {
        out_idx[(size_t)t * 8 + i] = (float)ti[i];
        out_w [(size_t)t * 8 + i] = (float)(wv[i] * scale);
    }
}

extern "C" void kernel_launch(void* const* d_in, const int* in_sizes, int n_in,
                              void* d_out, int out_size, void* d_ws, size_t ws_size,
                              hipStream_t stream)
{
    const float* x    = (const float*)d_in[0];
    const float* w    = (const float*)d_in[1];
    const float* bias = (const float*)d_in[2];
    float* out = (float*)d_out;
    double* scores = (double*)d_ws;   // 8192*256*8 = 16.8 MB scratch

    dim3 grid(N_EXP / BN, T_TOK / BM);   // 4 x 128 = 512 blocks
    gemm_scores_f64<<<grid, 256, 0, stream>>>(x, w, scores);
    route_topk<<<T_TOK / 256, 256, 0, stream>>>(scores, bias, out, out + (size_t)T_TOK * 8);
}

// Round 2
// 1077.506 us; speedup vs baseline: 1.2727x; 1.2727x over previous
//
#include <hip/hip_runtime.h>
#include <cmath>

#define T_TOK 8192
#define N_EXP 256
#define HID   7168
#define BM 64
#define BN 64
#define BK 16
#define LDP 66   // padded LDS row stride in doubles: 528 B, keeps 16B alignment,
                 // staging-write banks -> 2-way (free); +0/+1 pads would break
                 // b128 alignment or leave 8-way write conflicts.

// ---------------------------------------------------------------------------
// fp64-accumulated router GEMM + sigmoid epilogue, v2.
//   - LDS holds f64 (converted once at staging, not per-FMA)
//   - padded LDS rows kill the 8-way staging-write bank conflicts
//   - register prefetch of next k-tile overlaps HBM latency with FMA block
//   - scores written expert-major [E][T] so the routing kernel reads coalesced
// ---------------------------------------------------------------------------
__global__ __launch_bounds__(256, 2)
void gemm_scores_f64_v2(const float* __restrict__ x, const float* __restrict__ w,
                        double* __restrict__ sc /* [N_EXP][T_TOK] */)
{
    __shared__ double xs[BK][LDP];
    __shared__ double ws[BK][LDP];
    const int tid = threadIdx.x;
    const int e0 = blockIdx.x * BN;
    const int t0 = blockIdx.y * BM;
    const int tx = tid & 15;    // expert micro-tile
    const int ty = tid >> 4;    // token  micro-tile
    const int sm  = tid >> 2;   // staging row 0..63
    const int skq = tid & 3;    // staging float4 within BK=16

    const float* xp = x + (size_t)(t0 + sm) * HID + skq * 4;
    const float* wp = w + (size_t)(e0 + sm) * HID + skq * 4;

    double acc[4][4];
#pragma unroll
    for (int i = 0; i < 4; ++i)
#pragma unroll
        for (int j = 0; j < 4; ++j) acc[i][j] = 0.0;

    float4 xv = *(const float4*)xp;
    float4 wv = *(const float4*)wp;

    for (int k0 = 0; k0 < HID; k0 += BK) {
        __syncthreads();   // previous compute must be done before overwrite
        xs[skq * 4 + 0][sm] = (double)xv.x;
        xs[skq * 4 + 1][sm] = (double)xv.y;
        xs[skq * 4 + 2][sm] = (double)xv.z;
        xs[skq * 4 + 3][sm] = (double)xv.w;
        ws[skq * 4 + 0][sm] = (double)wv.x;
        ws[skq * 4 + 1][sm] = (double)wv.y;
        ws[skq * 4 + 2][sm] = (double)wv.z;
        ws[skq * 4 + 3][sm] = (double)wv.w;
        __syncthreads();
        if (k0 + BK < HID) {   // prefetch next tile; overlaps with FMA block
            xv = *(const float4*)(xp + k0 + BK);
            wv = *(const float4*)(wp + k0 + BK);
        }
#pragma unroll
        for (int kk = 0; kk < BK; ++kk) {
            const double a0 = xs[kk][ty * 4 + 0];
            const double a1 = xs[kk][ty * 4 + 1];
            const double a2 = xs[kk][ty * 4 + 2];
            const double a3 = xs[kk][ty * 4 + 3];
            const double b0 = ws[kk][tx * 4 + 0];
            const double b1 = ws[kk][tx * 4 + 1];
            const double b2 = ws[kk][tx * 4 + 2];
            const double b3 = ws[kk][tx * 4 + 3];
            acc[0][0] += a0 * b0; acc[0][1] += a0 * b1; acc[0][2] += a0 * b2; acc[0][3] += a0 * b3;
            acc[1][0] += a1 * b0; acc[1][1] += a1 * b1; acc[1][2] += a1 * b2; acc[1][3] += a1 * b3;
            acc[2][0] += a2 * b0; acc[2][1] += a2 * b1; acc[2][2] += a2 * b2; acc[2][3] += a2 * b3;
            acc[3][0] += a3 * b0; acc[3][1] += a3 * b1; acc[3][2] += a3 * b2; acc[3][3] += a3 * b3;
        }
    }

#pragma unroll
    for (int i = 0; i < 4; ++i) {
        const int t = t0 + ty * 4 + i;
#pragma unroll
        for (int j = 0; j < 4; ++j) {
            const int e = e0 + tx * 4 + j;
            sc[(size_t)e * T_TOK + t] = 1.0 / (1.0 + exp(-acc[i][j]));
        }
    }
}

// ---------------------------------------------------------------------------
// Routing v2: one thread per token, scores read coalesced from [E][T].
// All rank decisions in fp64, exact top_k tie semantics (lower index wins).
// ---------------------------------------------------------------------------
__global__ __launch_bounds__(64)
void route_topk_v2(const double* __restrict__ sc, const float* __restrict__ bias,
                   float* __restrict__ out_idx, float* __restrict__ out_w)
{
    __shared__ double bs[N_EXP];
    const int tid = threadIdx.x;
#pragma unroll
    for (int i = 0; i < 4; ++i) bs[tid + i * 64] = (double)bias[tid + i * 64];
    __syncthreads();

    const int t = blockIdx.x * 64 + tid;

    // Pass A: per-group top-2 sums.
    double gs[8];
#pragma unroll
    for (int g = 0; g < 8; ++g) {
        double m1 = -1e300, m2 = -1e300;
        for (int j = 0; j < 32; ++j) {
            const int e = g * 32 + j;
            const double v = sc[(size_t)e * T_TOK + t] + bs[e];
            if (v > m2) {
                if (v > m1) { m2 = m1; m1 = v; } else { m2 = v; }
            }
        }
        gs[g] = m1 + m2;
    }

    // Top-4 groups; strict > keeps lowest index on ties.
    int gm = 0;
#pragma unroll
    for (int r = 0; r < 4; ++r) {
        int best = 0; double bv = -1e300;
#pragma unroll
        for (int g = 0; g < 8; ++g) {
            const bool taken = (gm >> g) & 1;
            if (!taken && gs[g] > bv) { bv = gs[g]; best = g; }
        }
        gm |= (1 << best);
    }

    // Pass B: stable top-8 over masked scores (masked-out contribute 0.0),
    // early-out insertion (tv[7] guard), fully-unrolled register sort network.
    double tv[8]; int ti[8];
#pragma unroll
    for (int i = 0; i < 8; ++i) { tv[i] = -1e300; ti[i] = 0; }
    for (int e = 0; e < N_EXP; ++e) {
        const double v = sc[(size_t)e * T_TOK + t] + bs[e];
        double cv = ((gm >> (e >> 5)) & 1) ? v : 0.0;
        if (cv > tv[7]) {
            int ci = e;
#pragma unroll
            for (int p = 0; p < 8; ++p) {
                const bool sw = cv > tv[p];  // strict: equal keeps earlier idx
                const double od = tv[p]; const int oi = ti[p];
                tv[p] = sw ? cv : od; ti[p] = sw ? ci : oi;
                cv    = sw ? od : cv; ci    = sw ? oi : ci;
            }
        }
    }

    double wv[8]; double wsum = 0.0;
#pragma unroll
    for (int i = 0; i < 8; ++i) { wv[i] = sc[(size_t)ti[i] * T_TOK + t]; wsum += wv[i]; }
    const double scale = 2.5 / (wsum + 1e-20);
#pragma unroll
    for (int i = 0; i < 8; ++i) {
        out_idx[(size_t)t * 8 + i] = (float)ti[i];
        out_w [(size_t)t * 8 + i] = (float)(wv[i] * scale);
    }
}

extern "C" void kernel_launch(void* const* d_in, const int* in_sizes, int n_in,
                              void* d_out, int out_size, void* d_ws, size_t ws_size,
                              hipStream_t stream)
{
    const float* x    = (const float*)d_in[0];
    const float* w    = (const float*)d_in[1];
    const float* bias = (const float*)d_in[2];
    float* out = (float*)d_out;
    double* sc = (double*)d_ws;   // [N_EXP][T_TOK] doubles = 16.8 MB

    dim3 grid(N_EXP / BN, T_TOK / BM);   // 4 x 128 = 512 blocks
    gemm_scores_f64_v2<<<grid, 256, 0, stream>>>(x, w, sc);
    route_topk_v2<<<T_TOK / 64, 64, 0, stream>>>(sc, bias, out, out + (size_t)T_TOK * 8);
}

// Round 4
// 928.025 us; speedup vs baseline: 1.4777x; 1.1611x over previous
//
#include <hip/hip_runtime.h>
#include <cmath>

#define T_TOK 8192
#define N_EXP 256
#define HID   7168
#define BM 128
#define BN 32
#define BK 16
#define LDMX 132
#define LDNX 34

typedef double d4 __attribute__((ext_vector_type(4)));

// ---------------------------------------------------------------------------
// fp64 GEMM on the MFMA pipe with a SELF-CALIBRATING epilogue.
// Two probe MFMAs decode the C/D register->(row,col) mapping on-device, so
// correctness no longer depends on the (unverified-for-f64) layout claim.
// Block tile 128(M=tokens) x 32(N=experts), 4 waves stacked in M, each wave
// 32x32 via 2x2 MFMA subtiles, BK=16.
// Scores written EXPERT-MAJOR sc[e][t] (feeds the proven routing kernel).
// ---------------------------------------------------------------------------
__global__ __launch_bounds__(256, 2)
void gemm_scores_mfma64_cal(const float* __restrict__ x, const float* __restrict__ w,
                            double* __restrict__ sc /* [N_EXP][T_TOK] */)
{
    __shared__ double xs[BK][LDMX];
    __shared__ double wsh[BK][LDNX];
    const int tid  = threadIdx.x;
    const int wave = tid >> 6;
    const int lane = tid & 63;
    const int e0 = blockIdx.x * BN;
    const int t0 = blockIdx.y * BM;
    const int la = lane & 15;   // assumed m/n lane coordinate
    const int kq = lane >> 4;   // assumed k lane coordinate

    // ---- self-calibration probes (exact small integers in fp64) ----
    // probe1: A[m][0]=m, B[0][n]=1  -> D[m][n]=m  : reg i's ROW
    // probe2: A[m][0]=1, B[0][n]=n  -> D[m][n]=n  : reg i's COL
    const double p_idx = (kq == 0) ? (double)la : 0.0;
    const double p_one = (kq == 0) ? 1.0 : 0.0;
    d4 prow = (d4)(0.0), pcol = (d4)(0.0);
    prow = __builtin_amdgcn_mfma_f64_16x16x4f64(p_idx, p_one, prow, 0, 0, 0);
    pcol = __builtin_amdgcn_mfma_f64_16x16x4f64(p_one, p_idx, pcol, 0, 0, 0);
    int rrow[4], rcol[4];
#pragma unroll
    for (int i = 0; i < 4; ++i) {
        rrow[i] = (int)(prow[i] + 0.5);
        rcol[i] = (int)(pcol[i] + 0.5);
    }

    // staging: x-tile 128 rows x 16 k = 512 float4 -> 2/thread
    const int xrow = tid >> 2;
    const int xq   = tid & 3;
    const float* xp0 = x + (size_t)(t0 + xrow) * HID + xq * 4;
    const float* xp1 = x + (size_t)(t0 + xrow + 64) * HID + xq * 4;
    const int wrow = (tid >> 2) & 31;   // valid when tid<128
    const float* wp = w + (size_t)(e0 + wrow) * HID + xq * 4;

    d4 acc[2][2];
#pragma unroll
    for (int i = 0; i < 2; ++i)
#pragma unroll
        for (int j = 0; j < 2; ++j) acc[i][j] = (d4)(0.0);

    float4 xv0 = *(const float4*)xp0;
    float4 xv1 = *(const float4*)xp1;
    float4 wv  = (tid < 128) ? *(const float4*)wp : float4{0.f, 0.f, 0.f, 0.f};

    const int m0 = wave * 32;

    for (int k0 = 0; k0 < HID; k0 += BK) {
        __syncthreads();
        xs[4 * xq + 0][xrow] = (double)xv0.x;
        xs[4 * xq + 1][xrow] = (double)xv0.y;
        xs[4 * xq + 2][xrow] = (double)xv0.z;
        xs[4 * xq + 3][xrow] = (double)xv0.w;
        xs[4 * xq + 0][xrow + 64] = (double)xv1.x;
        xs[4 * xq + 1][xrow + 64] = (double)xv1.y;
        xs[4 * xq + 2][xrow + 64] = (double)xv1.z;
        xs[4 * xq + 3][xrow + 64] = (double)xv1.w;
        if (tid < 128) {
            wsh[4 * xq + 0][wrow] = (double)wv.x;
            wsh[4 * xq + 1][wrow] = (double)wv.y;
            wsh[4 * xq + 2][wrow] = (double)wv.z;
            wsh[4 * xq + 3][wrow] = (double)wv.w;
        }
        __syncthreads();
        if (k0 + BK < HID) {   // register prefetch overlaps the MFMA block
            xv0 = *(const float4*)(xp0 + k0 + BK);
            xv1 = *(const float4*)(xp1 + k0 + BK);
            if (tid < 128) wv = *(const float4*)(wp + k0 + BK);
        }
#pragma unroll
        for (int s = 0; s < 4; ++s) {
            const int kk = s * 4 + kq;
            const double a0 = xs[kk][m0 + la];
            const double a1 = xs[kk][m0 + 16 + la];
            const double b0 = wsh[kk][la];
            const double b1 = wsh[kk][16 + la];
            acc[0][0] = __builtin_amdgcn_mfma_f64_16x16x4f64(a0, b0, acc[0][0], 0, 0, 0);
            acc[0][1] = __builtin_amdgcn_mfma_f64_16x16x4f64(a0, b1, acc[0][1], 0, 0, 0);
            acc[1][0] = __builtin_amdgcn_mfma_f64_16x16x4f64(a1, b0, acc[1][0], 0, 0, 0);
            acc[1][1] = __builtin_amdgcn_mfma_f64_16x16x4f64(a1, b1, acc[1][1], 0, 0, 0);
        }
    }

    // calibrated epilogue: reg i of subtile (mi,ni) holds D[rrow[i]][rcol[i]]
#pragma unroll
    for (int mi = 0; mi < 2; ++mi)
#pragma unroll
        for (int ni = 0; ni < 2; ++ni)
#pragma unroll
            for (int i = 0; i < 4; ++i) {
                const int t = t0 + m0 + mi * 16 + rrow[i];
                const int e = e0 + ni * 16 + rcol[i];
                sc[(size_t)e * T_TOK + t] = 1.0 / (1.0 + exp(-acc[mi][ni][i]));
            }
}

// ---------------------------------------------------------------------------
// Routing — VERBATIM the round-2 proven-PASS kernel (coalesced [E][T] reads,
// fp64 end-to-end, exact jax.lax.top_k tie semantics).
// ---------------------------------------------------------------------------
__global__ __launch_bounds__(64)
void route_topk_v2(const double* __restrict__ sc, const float* __restrict__ bias,
                   float* __restrict__ out_idx, float* __restrict__ out_w)
{
    __shared__ double bs[N_EXP];
    const int tid = threadIdx.x;
#pragma unroll
    for (int i = 0; i < 4; ++i) bs[tid + i * 64] = (double)bias[tid + i * 64];
    __syncthreads();

    const int t = blockIdx.x * 64 + tid;

    double gs[8];
#pragma unroll
    for (int g = 0; g < 8; ++g) {
        double m1 = -1e300, m2 = -1e300;
        for (int j = 0; j < 32; ++j) {
            const int e = g * 32 + j;
            const double v = sc[(size_t)e * T_TOK + t] + bs[e];
            if (v > m2) {
                if (v > m1) { m2 = m1; m1 = v; } else { m2 = v; }
            }
        }
        gs[g] = m1 + m2;
    }

    int gm = 0;
#pragma unroll
    for (int r = 0; r < 4; ++r) {
        int best = 0; double bv = -1e300;
#pragma unroll
        for (int g = 0; g < 8; ++g) {
            const bool taken = (gm >> g) & 1;
            if (!taken && gs[g] > bv) { bv = gs[g]; best = g; }
        }
        gm |= (1 << best);
    }

    double tv[8]; int ti[8];
#pragma unroll
    for (int i = 0; i < 8; ++i) { tv[i] = -1e300; ti[i] = 0; }
    for (int e = 0; e < N_EXP; ++e) {
        const double v = sc[(size_t)e * T_TOK + t] + bs[e];
        double cv = ((gm >> (e >> 5)) & 1) ? v : 0.0;
        if (cv > tv[7]) {
            int ci = e;
#pragma unroll
            for (int p = 0; p < 8; ++p) {
                const bool sw = cv > tv[p];
                const double od = tv[p]; const int oi = ti[p];
                tv[p] = sw ? cv : od; ti[p] = sw ? ci : oi;
                cv    = sw ? od : cv; ci    = sw ? oi : ci;
            }
        }
    }

    double wv[8]; double wsum = 0.0;
#pragma unroll
    for (int i = 0; i < 8; ++i) { wv[i] = sc[(size_t)ti[i] * T_TOK + t]; wsum += wv[i]; }
    const double scale = 2.5 / (wsum + 1e-20);
#pragma unroll
    for (int i = 0; i < 8; ++i) {
        out_idx[(size_t)t * 8 + i] = (float)ti[i];
        out_w [(size_t)t * 8 + i] = (float)(wv[i] * scale);
    }
}

extern "C" void kernel_launch(void* const* d_in, const int* in_sizes, int n_in,
                              void* d_out, int out_size, void* d_ws, size_t ws_size,
                              hipStream_t stream)
{
    const float* x    = (const float*)d_in[0];
    const float* w    = (const float*)d_in[1];
    const float* bias = (const float*)d_in[2];
    float* out = (float*)d_out;
    double* sc = (double*)d_ws;   // [N_EXP][T_TOK] doubles = 16.8 MB

    dim3 grid(N_EXP / BN, T_TOK / BM);   // 8 x 64 = 512 blocks
    gemm_scores_mfma64_cal<<<grid, 256, 0, stream>>>(x, w, sc);
    route_topk_v2<<<T_TOK / 64, 64, 0, stream>>>(sc, bias, out, out + (size_t)T_TOK * 8);
}

// Round 5
// 861.044 us; speedup vs baseline: 1.5926x; 1.0778x over previous
//
#include <hip/hip_runtime.h>
#include <cmath>

#define T_TOK 8192
#define N_EXP 256
#define HID   7168
#define BM 64
#define BN 32
#define BK 32
#define LDK 34   // padded row stride (doubles): 272 B = 17*16 B -> b128-aligned
                 // rows; staging b128 writes land conflict-free (8-cycle floor),
                 // b64 fragment reads at the 4-cycle floor (2 lanes/bank).

typedef double d4 __attribute__((ext_vector_type(4)));

// ---------------------------------------------------------------------------
// fp64 MFMA GEMM v5: occupancy fix. 64x32 tile, BK=32, grid 8x128 = 1024
// blocks = 4 blocks/CU = 16 waves/CU (vs 8 before) so barrier drains hide
// behind other blocks' MFMA chains. 4 waves stacked in M (16 rows each),
// each wave 1x2 subtiles of 16x16. Self-calibrating C/D epilogue (proven
// round 4). Scores written expert-major sc[e][t] for the routing kernel.
// ---------------------------------------------------------------------------
__global__ __launch_bounds__(256, 4)
void gemm_scores_mfma64_v5(const float* __restrict__ x, const float* __restrict__ w,
                           double* __restrict__ sc /* [N_EXP][T_TOK] */)
{
    __shared__ double xs[BM][LDK];
    __shared__ double wsh[BN][LDK];
    const int tid  = threadIdx.x;
    const int wave = tid >> 6;
    const int lane = tid & 63;
    const int e0 = blockIdx.x * BN;
    const int t0 = blockIdx.y * BM;
    const int la = lane & 15;
    const int kq = lane >> 4;

    // ---- self-calibration probes (exact small ints; decodes C/D mapping) ----
    const double p_idx = (kq == 0) ? (double)la : 0.0;
    const double p_one = (kq == 0) ? 1.0 : 0.0;
    d4 prow = (d4)(0.0), pcol = (d4)(0.0);
    prow = __builtin_amdgcn_mfma_f64_16x16x4f64(p_idx, p_one, prow, 0, 0, 0);
    pcol = __builtin_amdgcn_mfma_f64_16x16x4f64(p_one, p_idx, pcol, 0, 0, 0);
    int rrow[4], rcol[4];
#pragma unroll
    for (int i = 0; i < 4; ++i) {
        rrow[i] = (int)(prow[i] + 0.5);
        rcol[i] = (int)(pcol[i] + 0.5);
    }

    // staging: x-tile 64 rows x 32 k = 512 float4 -> 2/thread (rows r, r+32)
    //          w-tile 32 rows x 32 k = 256 float4 -> 1/thread
    const int xrow = tid >> 3;          // 0..31
    const int sq   = tid & 7;           // float4 slot in k (k = 4*sq..4*sq+3)
    const float* xp0 = x + (size_t)(t0 + xrow) * HID + sq * 4;
    const float* xp1 = x + (size_t)(t0 + xrow + 32) * HID + sq * 4;
    const float* wp  = w + (size_t)(e0 + xrow) * HID + sq * 4;   // xrow<32 ✓

    d4 acc0 = (d4)(0.0), acc1 = (d4)(0.0);

    float4 xv0 = *(const float4*)xp0;
    float4 xv1 = *(const float4*)xp1;
    float4 wv  = *(const float4*)wp;

    const int m0 = wave * 16;

    for (int k0 = 0; k0 < HID; k0 += BK) {
        __syncthreads();
        {   // 16B-aligned double2 stores: (row*34 + 4*sq) doubles, 272B rows
            double2* xd0 = (double2*)&xs[xrow][4 * sq];
            xd0[0] = double2{(double)xv0.x, (double)xv0.y};
            xd0[1] = double2{(double)xv0.z, (double)xv0.w};
            double2* xd1 = (double2*)&xs[xrow + 32][4 * sq];
            xd1[0] = double2{(double)xv1.x, (double)xv1.y};
            xd1[1] = double2{(double)xv1.z, (double)xv1.w};
            double2* wd = (double2*)&wsh[xrow][4 * sq];
            wd[0] = double2{(double)wv.x, (double)wv.y};
            wd[1] = double2{(double)wv.z, (double)wv.w};
        }
        __syncthreads();
        if (k0 + BK < HID) {   // register prefetch overlaps the MFMA block
            xv0 = *(const float4*)(xp0 + k0 + BK);
            xv1 = *(const float4*)(xp1 + k0 + BK);
            wv  = *(const float4*)(wp  + k0 + BK);
        }
#pragma unroll
        for (int s = 0; s < 8; ++s) {
            const int kk = s * 4 + kq;
            const double a  = xs[m0 + la][kk];
            const double b0 = wsh[la][kk];
            const double b1 = wsh[16 + la][kk];
            acc0 = __builtin_amdgcn_mfma_f64_16x16x4f64(a, b0, acc0, 0, 0, 0);
            acc1 = __builtin_amdgcn_mfma_f64_16x16x4f64(a, b1, acc1, 0, 0, 0);
        }
    }

    // calibrated epilogue: reg i holds D[rrow[i]][rcol[i]] of its subtile
#pragma unroll
    for (int i = 0; i < 4; ++i) {
        const int t = t0 + m0 + rrow[i];
        sc[(size_t)(e0 + rcol[i]) * T_TOK + t]      = 1.0 / (1.0 + exp(-acc0[i]));
        sc[(size_t)(e0 + 16 + rcol[i]) * T_TOK + t] = 1.0 / (1.0 + exp(-acc1[i]));
    }
}

// ---------------------------------------------------------------------------
// Routing — VERBATIM the proven-PASS kernel (coalesced [E][T] reads,
// fp64 end-to-end, exact jax.lax.top_k tie semantics).
// ---------------------------------------------------------------------------
__global__ __launch_bounds__(64)
void route_topk_v2(const double* __restrict__ sc, const float* __restrict__ bias,
                   float* __restrict__ out_idx, float* __restrict__ out_w)
{
    __shared__ double bs[N_EXP];
    const int tid = threadIdx.x;
#pragma unroll
    for (int i = 0; i < 4; ++i) bs[tid + i * 64] = (double)bias[tid + i * 64];
    __syncthreads();

    const int t = blockIdx.x * 64 + tid;

    double gs[8];
#pragma unroll
    for (int g = 0; g < 8; ++g) {
        double m1 = -1e300, m2 = -1e300;
        for (int j = 0; j < 32; ++j) {
            const int e = g * 32 + j;
            const double v = sc[(size_t)e * T_TOK + t] + bs[e];
            if (v > m2) {
                if (v > m1) { m2 = m1; m1 = v; } else { m2 = v; }
            }
        }
        gs[g] = m1 + m2;
    }

    int gm = 0;
#pragma unroll
    for (int r = 0; r < 4; ++r) {
        int best = 0; double bv = -1e300;
#pragma unroll
        for (int g = 0; g < 8; ++g) {
            const bool taken = (gm >> g) & 1;
            if (!taken && gs[g] > bv) { bv = gs[g]; best = g; }
        }
        gm |= (1 << best);
    }

    double tv[8]; int ti[8];
#pragma unroll
    for (int i = 0; i < 8; ++i) { tv[i] = -1e300; ti[i] = 0; }
    for (int e = 0; e < N_EXP; ++e) {
        const double v = sc[(size_t)e * T_TOK + t] + bs[e];
        double cv = ((gm >> (e >> 5)) & 1) ? v : 0.0;
        if (cv > tv[7]) {
            int ci = e;
#pragma unroll
            for (int p = 0; p < 8; ++p) {
                const bool sw = cv > tv[p];
                const double od = tv[p]; const int oi = ti[p];
                tv[p] = sw ? cv : od; ti[p] = sw ? ci : oi;
                cv    = sw ? od : cv; ci    = sw ? oi : ci;
            }
        }
    }

    double wv[8]; double wsum = 0.0;
#pragma unroll
    for (int i = 0; i < 8; ++i) { wv[i] = sc[(size_t)ti[i] * T_TOK + t]; wsum += wv[i]; }
    const double scale = 2.5 / (wsum + 1e-20);
#pragma unroll
    for (int i = 0; i < 8; ++i) {
        out_idx[(size_t)t * 8 + i] = (float)ti[i];
        out_w [(size_t)t * 8 + i] = (float)(wv[i] * scale);
    }
}

extern "C" void kernel_launch(void* const* d_in, const int* in_sizes, int n_in,
                              void* d_out, int out_size, void* d_ws, size_t ws_size,
                              hipStream_t stream)
{
    const float* x    = (const float*)d_in[0];
    const float* w    = (const float*)d_in[1];
    const float* bias = (const float*)d_in[2];
    float* out = (float*)d_out;
    double* sc = (double*)d_ws;   // [N_EXP][T_TOK] doubles = 16.8 MB

    dim3 grid(N_EXP / BN, T_TOK / BM);   // 8 x 128 = 1024 blocks, 4/CU
    gemm_scores_mfma64_v5<<<grid, 256, 0, stream>>>(x, w, sc);
    route_topk_v2<<<T_TOK / 64, 64, 0, stream>>>(sc, bias, out, out + (size_t)T_TOK * 8);
}

// Round 6
// 839.135 us; speedup vs baseline: 1.6342x; 1.0261x over previous
//
#include <hip/hip_runtime.h>
#include <cmath>

#define T_TOK 8192
#define N_EXP 256
#define HID   7168
#define BM 64
#define BN 32
#define BK 32
#define LDX 65   // xs row stride (doubles): k-major rows; 130 words = 2 mod 32
#define LDW 33   // wsh row stride: 66 words = 2 mod 32

typedef double d4 __attribute__((ext_vector_type(4)));

// ---------------------------------------------------------------------------
// fp64 MFMA GEMM v6: k-major LDS staging (xs[k][token], wsh[k][expert]) with
// b64 stores -> start banks (8q+2j+2r)%32, uniform 4 lanes/bank = phase floor
// (v5's [row][k] float4-chunk stores were 8 lanes/start -> 4x floor, 35% of
// wall). Fragment reads bank = 8s+2(kq+la): uniform 4/bank. Calibrated C/D
// epilogue (proven r4/r5). Scores written TOKEN-major sc[t][e] for routing.
// ---------------------------------------------------------------------------
__global__ __launch_bounds__(256, 4)
void gemm_scores_mfma64_v6(const float* __restrict__ x, const float* __restrict__ w,
                           double* __restrict__ sc /* [T_TOK][N_EXP] */)
{
    __shared__ double xs[BK][LDX];
    __shared__ double wsh[BK][LDW];
    const int tid  = threadIdx.x;
    const int wave = tid >> 6;
    const int lane = tid & 63;
    const int e0 = blockIdx.x * BN;
    const int t0 = blockIdx.y * BM;
    const int la = lane & 15;
    const int kq = lane >> 4;

    // ---- self-calibration probes: decode C/D reg->(row,col) on-device ----
    const double p_idx = (kq == 0) ? (double)la : 0.0;
    const double p_one = (kq == 0) ? 1.0 : 0.0;
    d4 prow = (d4)(0.0), pcol = (d4)(0.0);
    prow = __builtin_amdgcn_mfma_f64_16x16x4f64(p_idx, p_one, prow, 0, 0, 0);
    pcol = __builtin_amdgcn_mfma_f64_16x16x4f64(p_one, p_idx, pcol, 0, 0, 0);
    int rrow[4], rcol[4];
#pragma unroll
    for (int i = 0; i < 4; ++i) {
        rrow[i] = (int)(prow[i] + 0.5);
        rcol[i] = (int)(pcol[i] + 0.5);
    }

    // staging ownership: thread (r = tid>>3 in 0..31, q = tid&7)
    const int r = tid >> 3;
    const int q = tid & 7;
    const float* xp0 = x + (size_t)(t0 + r) * HID + q * 4;
    const float* xp1 = x + (size_t)(t0 + r + 32) * HID + q * 4;
    const float* wp  = w + (size_t)(e0 + r) * HID + q * 4;

    d4 acc0 = (d4)(0.0), acc1 = (d4)(0.0);

    float4 xv0 = *(const float4*)xp0;
    float4 xv1 = *(const float4*)xp1;
    float4 wv  = *(const float4*)wp;

    const int m0 = wave * 16;

    for (int k0 = 0; k0 < HID; k0 += BK) {
        __syncthreads();
        {   // k-major b64 stores: xs[4q+j][r] — uniform bank spread
            const float a0[4] = {xv0.x, xv0.y, xv0.z, xv0.w};
            const float a1[4] = {xv1.x, xv1.y, xv1.z, xv1.w};
            const float b [4] = {wv.x,  wv.y,  wv.z,  wv.w};
#pragma unroll
            for (int j = 0; j < 4; ++j) {
                xs[4 * q + j][r]      = (double)a0[j];
                xs[4 * q + j][r + 32] = (double)a1[j];
                wsh[4 * q + j][r]     = (double)b[j];
            }
        }
        __syncthreads();
        if (k0 + BK < HID) {   // register prefetch overlaps the MFMA block
            xv0 = *(const float4*)(xp0 + k0 + BK);
            xv1 = *(const float4*)(xp1 + k0 + BK);
            wv  = *(const float4*)(wp  + k0 + BK);
        }
#pragma unroll
        for (int s = 0; s < 8; ++s) {
            const int kk = s * 4 + kq;
            const double a  = xs[kk][m0 + la];
            const double b0 = wsh[kk][la];
            const double b1 = wsh[kk][16 + la];
            acc0 = __builtin_amdgcn_mfma_f64_16x16x4f64(a, b0, acc0, 0, 0, 0);
            acc1 = __builtin_amdgcn_mfma_f64_16x16x4f64(a, b1, acc1, 0, 0, 0);
        }
    }

    // calibrated epilogue, TOKEN-major scores
#pragma unroll
    for (int i = 0; i < 4; ++i) {
        const size_t t = t0 + m0 + rrow[i];
        sc[t * N_EXP + e0 + rcol[i]]      = 1.0 / (1.0 + exp(-acc0[i]));
        sc[t * N_EXP + e0 + 16 + rcol[i]] = 1.0 / (1.0 + exp(-acc1[i]));
    }
}

// ---------------------------------------------------------------------------
// Routing v3: ONE WAVE PER TOKEN (8192 waves vs v2's 128). Lane l owns
// experts 4l..4l+3; one contiguous 2 KB row read per wave. Group top-2 via
// butterfly in 8-lane subgroups; top-8 via 8 rounds of wave argmax
// (value desc, index asc) — exact jax.lax.top_k semantics, fp64 throughout.
// ---------------------------------------------------------------------------
__global__ __launch_bounds__(256)
void route_topk_v3(const double* __restrict__ sc, const float* __restrict__ bias,
                   float* __restrict__ out_idx, float* __restrict__ out_w)
{
    const int wave = threadIdx.x >> 6;
    const int lane = threadIdx.x & 63;
    const int t = blockIdx.x * 4 + wave;
    const double* srow = sc + (size_t)t * N_EXP;

    const float4 bf = *(const float4*)(bias + lane * 4);
    double raw[4], v[4];
#pragma unroll
    for (int j = 0; j < 4; ++j) raw[j] = srow[4 * lane + j];
    v[0] = raw[0] + (double)bf.x;
    v[1] = raw[1] + (double)bf.y;
    v[2] = raw[2] + (double)bf.z;
    v[3] = raw[3] + (double)bf.w;

    // lane-local top-2, then butterfly merge across the 8-lane group
    double m1 = -1e300, m2 = -1e300;
#pragma unroll
    for (int j = 0; j < 4; ++j) {
        if (v[j] > m1) { m2 = m1; m1 = v[j]; }
        else if (v[j] > m2) { m2 = v[j]; }
    }
#pragma unroll
    for (int d = 1; d <= 4; d <<= 1) {
        const double o1 = __shfl_xor(m1, d);
        const double o2 = __shfl_xor(m2, d);
        if (o1 > m1) { m2 = fmax(m1, o2); m1 = o1; }
        else         { m2 = fmax(m2, o1); }
    }
    const double gsum = m1 + m2;

    double gq[8];
#pragma unroll
    for (int g = 0; g < 8; ++g) gq[g] = __shfl(gsum, g * 8);
    int gm = 0;
#pragma unroll
    for (int rr = 0; rr < 4; ++rr) {
        int best = 0; double bv = -1e300;
#pragma unroll
        for (int g = 0; g < 8; ++g) {
            const bool taken = (gm >> g) & 1;
            if (!taken && gq[g] > bv) { bv = gq[g]; best = g; }
        }
        gm |= (1 << best);
    }

    // masked candidates: masked-out experts contribute exactly 0.0 (reference)
    double cv[4];
    const bool inmask = (gm >> (lane >> 3)) & 1;
#pragma unroll
    for (int j = 0; j < 4; ++j) cv[j] = inmask ? v[j] : 0.0;

    double wsum = 0.0, my_w = 0.0;
    int my_i = 0;
#pragma unroll
    for (int rr = 0; rr < 8; ++rr) {
        double bv = cv[0]; int bj = 0;
#pragma unroll
        for (int j = 1; j < 4; ++j)
            if (cv[j] > bv) { bv = cv[j]; bj = j; }
        int bi = 4 * lane + bj;
        double braw = (bj == 0) ? raw[0] : (bj == 1) ? raw[1] : (bj == 2) ? raw[2] : raw[3];
#pragma unroll
        for (int d = 1; d < 64; d <<= 1) {
            const double ov  = __shfl_xor(bv, d);
            const int    oi  = __shfl_xor(bi, d);
            const double orw = __shfl_xor(braw, d);
            if (ov > bv || (ov == bv && oi < bi)) { bv = ov; bi = oi; braw = orw; }
        }
        wsum += braw;
        if (lane == rr) { my_i = bi; my_w = braw; }
        if ((bi >> 2) == lane) cv[bi & 3] = -1e300;   // owner retires winner
    }

    const double scale = 2.5 / (wsum + 1e-20);
    if (lane < 8) {
        out_idx[(size_t)t * 8 + lane] = (float)my_i;
        out_w [(size_t)t * 8 + lane] = (float)(my_w * scale);
    }
}

extern "C" void kernel_launch(void* const* d_in, const int* in_sizes, int n_in,
                              void* d_out, int out_size, void* d_ws, size_t ws_size,
                              hipStream_t stream)
{
    const float* x    = (const float*)d_in[0];
    const float* w    = (const float*)d_in[1];
    const float* bias = (const float*)d_in[2];
    float* out = (float*)d_out;
    double* sc = (double*)d_ws;   // [T_TOK][N_EXP] doubles = 16.8 MB

    dim3 grid(N_EXP / BN, T_TOK / BM);   // 8 x 128 = 1024 blocks, 4/CU
    gemm_scores_mfma64_v6<<<grid, 256, 0, stream>>>(x, w, sc);
    route_topk_v3<<<T_TOK / 4, 256, 0, stream>>>(sc, bias, out, out + (size_t)T_TOK * 8);
}

// Round 7
// 794.153 us; speedup vs baseline: 1.7268x; 1.0566x over previous
//
#include <hip/hip_runtime.h>
#include <cmath>

#define T_TOK 8192
#define N_EXP 256
#define HID   7168
#define RESCUE_CAP 2048
#define MTAU 4e-5     // expert-chain margin threshold (score space), ~3x the 5-sigma bf16-split error
#define GTAU 1.6e-4   // group-sum margin threshold (= 4*MTAU: group sums carry up to 4x score error)

typedef unsigned short u16;
typedef short bf16x8 __attribute__((ext_vector_type(8)));
typedef float f32x4 __attribute__((ext_vector_type(4)));
typedef double f64x4 __attribute__((ext_vector_type(4)));

__device__ __forceinline__ u16 bf16_rtne(float f) {
    unsigned u = __float_as_uint(f);
    u += 0x7FFFu + ((u >> 16) & 1u);
    return (u16)(u >> 16);
}
__device__ __forceinline__ float bf16_f(u16 h) { return __uint_as_float(((unsigned)h) << 16); }

// ---------------------------------------------------------------------------
// K0: zero the flag counter.
// ---------------------------------------------------------------------------
__global__ void zero_cnt(int* cnt) { if (threadIdx.x == 0) *cnt = 0; }

// ---------------------------------------------------------------------------
// K1: split w fp32 -> (wh, wl) bf16 pair. Exact: wl = bf16(w - float(wh)).
// ---------------------------------------------------------------------------
__global__ __launch_bounds__(256)
void wsplit(const float* __restrict__ w, u16* __restrict__ wh, u16* __restrict__ wl)
{
    const size_t base = ((size_t)blockIdx.x * 256 + threadIdx.x) * 8;
    const float4 f0 = *(const float4*)(w + base);
    const float4 f1 = *(const float4*)(w + base + 4);
    const float f[8] = {f0.x, f0.y, f0.z, f0.w, f1.x, f1.y, f1.z, f1.w};
    bf16x8 H, L;
#pragma unroll
    for (int i = 0; i < 8; ++i) {
        const u16 h = bf16_rtne(f[i]);
        H[i] = (short)h;
        L[i] = (short)bf16_rtne(f[i] - bf16_f(h));
    }
    *(bf16x8*)(wh + base) = H;
    *(bf16x8*)(wl + base) = L;
}

// ---------------------------------------------------------------------------
// K2: bf16-split router GEMM on the 2.4 PF MFMA pipe.
// logits[t][e] = x[t]·w[e] via hi*hi + hi*lo + lo*hi (lo*lo dropped; logit
// error 5sig ~3.5e-5). Tile: BM=32 tokens x BN=256 (all experts), BK=32,
// 512 threads (8 waves), each wave a 32x32 output (2x2 of 16x16x32 MFMA).
// Grid 256 blocks = 1/CU. bf16 C/D mapping decoded by on-device probes
// (technique proven r4-r6); A/B fragment maps are the HW-verified ones.
// ---------------------------------------------------------------------------
#define G1_S 40   // LDS row stride (ushorts): start bank-group (5m+q)%8 -> uniform 8 lanes/group
__global__ __launch_bounds__(512, 1)
void gemm_bf16split(const float* __restrict__ x, const u16* __restrict__ wh,
                    const u16* __restrict__ wl, float* __restrict__ logits)
{
    __shared__ u16 xhs[32][G1_S], xls[32][G1_S];
    __shared__ u16 whs[N_EXP][G1_S], wls[N_EXP][G1_S];
    const int tid = threadIdx.x;
    const int wave = tid >> 6, lane = tid & 63;
    const int t0 = blockIdx.x * 32;
    const int la = lane & 15, q8 = (lane >> 4) * 8;

    // calibration probes: D[m][n]=m then =n decodes reg->(row,col)
    bf16x8 pidx = (bf16x8)(short)0, pone = (bf16x8)(short)0;
    if ((lane >> 4) == 0) {
        pidx[0] = (short)bf16_rtne((float)la);
        pone[0] = (short)0x3F80;   // bf16(1.0)
    }
    f32x4 pr = __builtin_amdgcn_mfma_f32_16x16x32_bf16(pidx, pone, (f32x4)(0.f), 0, 0, 0);
    f32x4 pc = __builtin_amdgcn_mfma_f32_16x16x32_bf16(pone, pidx, (f32x4)(0.f), 0, 0, 0);
    int rrow[4], rcol[4];
#pragma unroll
    for (int i = 0; i < 4; ++i) {
        rrow[i] = (int)(pr[i] + 0.5f);
        rcol[i] = (int)(pc[i] + 0.5f);
    }

    // staging ownership: x: 2 floats/thread; w: 16 ushorts x2 dt /thread
    const int xr = tid >> 4;            // 0..31
    const int xc = (tid & 15) * 2;      // 0..30 even
    const float* xp = x + (size_t)(t0 + xr) * HID + xc;
    const int we = tid >> 1;            // 0..255
    const int wc = (tid & 1) * 16;
    const u16* whp = wh + (size_t)we * HID + wc;
    const u16* wlp = wl + (size_t)we * HID + wc;

    f32x4 acc[2][2];
#pragma unroll
    for (int i = 0; i < 2; ++i)
#pragma unroll
        for (int j = 0; j < 2; ++j) acc[i][j] = (f32x4)(0.f);

    float2 xv = *(const float2*)xp;
    int4 wa0 = *(const int4*)(whp);
    int4 wa1 = *(const int4*)(whp + 8);
    int4 wb0 = *(const int4*)(wlp);
    int4 wb1 = *(const int4*)(wlp + 8);

    const int wbase = wave * 32;

    for (int k0 = 0; k0 < HID; k0 += 32) {
        __syncthreads();
        {   // x: convert fp32 -> (hi, lo) bf16; residual subtraction is exact
            const u16 h0 = bf16_rtne(xv.x);
            const u16 l0 = bf16_rtne(xv.x - bf16_f(h0));
            const u16 h1 = bf16_rtne(xv.y);
            const u16 l1 = bf16_rtne(xv.y - bf16_f(h1));
            xhs[xr][xc] = h0; xhs[xr][xc + 1] = h1;
            xls[xr][xc] = l0; xls[xr][xc + 1] = l1;
            *(int4*)&whs[we][wc] = wa0; *(int4*)&whs[we][wc + 8] = wa1;
            *(int4*)&wls[we][wc] = wb0; *(int4*)&wls[we][wc + 8] = wb1;
        }
        __syncthreads();
        if (k0 + 32 < HID) {   // register prefetch overlaps MFMA block
            xv  = *(const float2*)(xp + k0 + 32);
            wa0 = *(const int4*)(whp + k0 + 32);
            wa1 = *(const int4*)(whp + k0 + 40);
            wb0 = *(const int4*)(wlp + k0 + 32);
            wb1 = *(const int4*)(wlp + k0 + 40);
        }
        bf16x8 Ah[2], Al[2], Bh[2], Bl[2];
#pragma unroll
        for (int mi = 0; mi < 2; ++mi) {
            Ah[mi] = *(const bf16x8*)&xhs[mi * 16 + la][q8];
            Al[mi] = *(const bf16x8*)&xls[mi * 16 + la][q8];
        }
#pragma unroll
        for (int ni = 0; ni < 2; ++ni) {
            Bh[ni] = *(const bf16x8*)&whs[wbase + ni * 16 + la][q8];
            Bl[ni] = *(const bf16x8*)&wls[wbase + ni * 16 + la][q8];
        }
#pragma unroll
        for (int mi = 0; mi < 2; ++mi)
#pragma unroll
            for (int ni = 0; ni < 2; ++ni) {
                acc[mi][ni] = __builtin_amdgcn_mfma_f32_16x16x32_bf16(Ah[mi], Bh[ni], acc[mi][ni], 0, 0, 0);
                acc[mi][ni] = __builtin_amdgcn_mfma_f32_16x16x32_bf16(Ah[mi], Bl[ni], acc[mi][ni], 0, 0, 0);
                acc[mi][ni] = __builtin_amdgcn_mfma_f32_16x16x32_bf16(Al[mi], Bh[ni], acc[mi][ni], 0, 0, 0);
            }
    }

#pragma unroll
    for (int mi = 0; mi < 2; ++mi)
#pragma unroll
        for (int ni = 0; ni < 2; ++ni)
#pragma unroll
            for (int i = 0; i < 4; ++i)
                logits[(size_t)(t0 + mi * 16 + rrow[i]) * N_EXP + wbase + ni * 16 + rcol[i]] = acc[mi][ni][i];
}

// ---------------------------------------------------------------------------
// K3: routing + margin flags. v3 wave-per-token logic (proven r6) on fp32
// logits (sigmoid in fp64). Extra: 9th expert round + 5th group round give
// decision margins; if any margin < tau the token is appended for rescue.
// ---------------------------------------------------------------------------
__global__ __launch_bounds__(256)
void route_flag(const float* __restrict__ logits, const float* __restrict__ bias,
                float* __restrict__ out_idx, float* __restrict__ out_w,
                int* __restrict__ cnt, int* __restrict__ list)
{
    const int wave = threadIdx.x >> 6;
    const int lane = threadIdx.x & 63;
    const int t = blockIdx.x * 4 + wave;

    const float4 lg = *(const float4*)(logits + (size_t)t * N_EXP + 4 * lane);
    const float4 bf = *(const float4*)(bias + 4 * lane);
    const float lgv[4] = {lg.x, lg.y, lg.z, lg.w};
    const float bfv[4] = {bf.x, bf.y, bf.z, bf.w};
    double raw[4], v[4];
#pragma unroll
    for (int j = 0; j < 4; ++j) {
        raw[j] = 1.0 / (1.0 + exp(-(double)lgv[j]));
        v[j] = raw[j] + (double)bfv[j];
    }

    // group top-2 sums via butterfly in 8-lane subgroups
    double m1 = -1e300, m2 = -1e300;
#pragma unroll
    for (int j = 0; j < 4; ++j) {
        if (v[j] > m1) { m2 = m1; m1 = v[j]; }
        else if (v[j] > m2) { m2 = v[j]; }
    }
#pragma unroll
    for (int d = 1; d <= 4; d <<= 1) {
        const double o1 = __shfl_xor(m1, d);
        const double o2 = __shfl_xor(m2, d);
        if (o1 > m1) { m2 = fmax(m1, o2); m1 = o1; }
        else         { m2 = fmax(m2, o1); }
    }
    const double gsum = m1 + m2;

    double gq[8];
#pragma unroll
    for (int g = 0; g < 8; ++g) gq[g] = __shfl(gsum, g * 8);
    int gm = 0;
    double g4v = -1e300, gmargin = 1e300;
#pragma unroll
    for (int rr = 0; rr < 5; ++rr) {
        int best = 0; double bv = -1e300;
#pragma unroll
        for (int g = 0; g < 8; ++g) {
            const bool taken = (gm >> g) & 1;
            if (!taken && gq[g] > bv) { bv = gq[g]; best = g; }
        }
        if (rr < 4) { gm |= (1 << best); g4v = bv; }
        else gmargin = g4v - bv;
    }

    double cv[4];
    const bool inmask = (gm >> (lane >> 3)) & 1;
#pragma unroll
    for (int j = 0; j < 4; ++j) cv[j] = inmask ? v[j] : 0.0;

    double wsum = 0.0, my_w = 0.0, prev = 0.0, mmin = 1e300;
    int my_i = 0;
#pragma unroll
    for (int rr = 0; rr < 9; ++rr) {
        double bv = cv[0]; int bj = 0;
#pragma unroll
        for (int j = 1; j < 4; ++j)
            if (cv[j] > bv) { bv = cv[j]; bj = j; }
        int bi = 4 * lane + bj;
        double braw = (bj == 0) ? raw[0] : (bj == 1) ? raw[1] : (bj == 2) ? raw[2] : raw[3];
#pragma unroll
        for (int d = 1; d < 64; d <<= 1) {
            const double ov  = __shfl_xor(bv, d);
            const int    oi  = __shfl_xor(bi, d);
            const double orw = __shfl_xor(braw, d);
            if (ov > bv || (ov == bv && oi < bi)) { bv = ov; bi = oi; braw = orw; }
        }
        if (rr > 0) mmin = fmin(mmin, prev - bv);
        prev = bv;
        if (rr < 8) {
            wsum += braw;
            if (lane == rr) { my_i = bi; my_w = braw; }
            if ((bi >> 2) == lane) cv[bi & 3] = -1e300;
        }
    }

    const double scale = 2.5 / (wsum + 1e-20);
    if (lane < 8) {
        out_idx[(size_t)t * 8 + lane] = (float)my_i;
        out_w [(size_t)t * 8 + lane] = (float)(my_w * scale);
    }
    const bool flag = (mmin < MTAU) || (gmargin < GTAU);
    if (flag && lane == 0) {
        const int idx = atomicAdd(cnt, 1);
        if (idx < RESCUE_CAP) list[idx] = t;
    }
}

// ---------------------------------------------------------------------------
// K4: fp64 rescue GEMM — verbatim r6-proven v6 structure, row-indirected
// through the flagged-token list. Writes fp64 sigmoid scores token-major.
// ---------------------------------------------------------------------------
#define R_LDX 65
#define R_LDW 33
__global__ __launch_bounds__(256, 4)
void rescue_gemm64(const float* __restrict__ x, const float* __restrict__ w,
                   const int* __restrict__ cnt, const int* __restrict__ list,
                   double* __restrict__ resc /* [RESCUE_CAP][N_EXP] */)
{
    const int nf = min(*cnt, RESCUE_CAP);
    const int t0 = blockIdx.y * 64;
    if (t0 >= nf) return;

    __shared__ double xs[32][R_LDX];
    __shared__ double wsh[32][R_LDW];
    const int tid  = threadIdx.x;
    const int wave = tid >> 6;
    const int lane = tid & 63;
    const int e0 = blockIdx.x * 32;
    const int la = lane & 15;
    const int kq = lane >> 4;

    const double p_idx = (kq == 0) ? (double)la : 0.0;
    const double p_one = (kq == 0) ? 1.0 : 0.0;
    f64x4 prow = (f64x4)(0.0), pcol = (f64x4)(0.0);
    prow = __builtin_amdgcn_mfma_f64_16x16x4f64(p_idx, p_one, prow, 0, 0, 0);
    pcol = __builtin_amdgcn_mfma_f64_16x16x4f64(p_one, p_idx, pcol, 0, 0, 0);
    int rrow[4], rcol[4];
#pragma unroll
    for (int i = 0; i < 4; ++i) {
        rrow[i] = (int)(prow[i] + 0.5);
        rcol[i] = (int)(pcol[i] + 0.5);
    }

    const int r = tid >> 3;
    const int q = tid & 7;
    const int tr0 = list[min(t0 + r, nf - 1)];
    const int tr1 = list[min(t0 + r + 32, nf - 1)];
    const float* xp0 = x + (size_t)tr0 * HID + q * 4;
    const float* xp1 = x + (size_t)tr1 * HID + q * 4;
    const float* wp  = w + (size_t)(e0 + r) * HID + q * 4;

    f64x4 acc0 = (f64x4)(0.0), acc1 = (f64x4)(0.0);
    float4 xv0 = *(const float4*)xp0;
    float4 xv1 = *(const float4*)xp1;
    float4 wv  = *(const float4*)wp;
    const int m0 = wave * 16;

    for (int k0 = 0; k0 < HID; k0 += 32) {
        __syncthreads();
        {
            const float a0[4] = {xv0.x, xv0.y, xv0.z, xv0.w};
            const float a1[4] = {xv1.x, xv1.y, xv1.z, xv1.w};
            const float b [4] = {wv.x,  wv.y,  wv.z,  wv.w};
#pragma unroll
            for (int j = 0; j < 4; ++j) {
                xs[4 * q + j][r]      = (double)a0[j];
                xs[4 * q + j][r + 32] = (double)a1[j];
                wsh[4 * q + j][r]     = (double)b[j];
            }
        }
        __syncthreads();
        if (k0 + 32 < HID) {
            xv0 = *(const float4*)(xp0 + k0 + 32);
            xv1 = *(const float4*)(xp1 + k0 + 32);
            wv  = *(const float4*)(wp  + k0 + 32);
        }
#pragma unroll
        for (int s = 0; s < 8; ++s) {
            const int kk = s * 4 + kq;
            const double a  = xs[kk][m0 + la];
            const double b0 = wsh[kk][la];
            const double b1 = wsh[kk][16 + la];
            acc0 = __builtin_amdgcn_mfma_f64_16x16x4f64(a, b0, acc0, 0, 0, 0);
            acc1 = __builtin_amdgcn_mfma_f64_16x16x4f64(a, b1, acc1, 0, 0, 0);
        }
    }

#pragma unroll
    for (int i = 0; i < 4; ++i) {
        const size_t lt = t0 + m0 + rrow[i];
        resc[lt * N_EXP + e0 + rcol[i]]      = 1.0 / (1.0 + exp(-acc0[i]));
        resc[lt * N_EXP + e0 + 16 + rcol[i]] = 1.0 / (1.0 + exp(-acc1[i]));
    }
}

// ---------------------------------------------------------------------------
// K5: fp64 rescue routing — verbatim r6-proven v3 body on rescue scores,
// overwriting the flagged tokens' output rows.
// ---------------------------------------------------------------------------
__global__ __launch_bounds__(256)
void rescue_route(const double* __restrict__ resc, const float* __restrict__ bias,
                  const int* __restrict__ cnt, const int* __restrict__ list,
                  float* __restrict__ out_idx, float* __restrict__ out_w)
{
    const int nf = min(*cnt, RESCUE_CAP);
    const int wave = threadIdx.x >> 6;
    const int lane = threadIdx.x & 63;
    const int i_tok = blockIdx.x * 4 + wave;
    if (i_tok >= nf) return;
    const int t = list[i_tok];
    const double* srow = resc + (size_t)i_tok * N_EXP;

    const float4 bf = *(const float4*)(bias + lane * 4);
    const float bfv[4] = {bf.x, bf.y, bf.z, bf.w};
    double raw[4], v[4];
#pragma unroll
    for (int j = 0; j < 4; ++j) {
        raw[j] = srow[4 * lane + j];
        v[j] = raw[j] + (double)bfv[j];
    }

    double m1 = -1e300, m2 = -1e300;
#pragma unroll
    for (int j = 0; j < 4; ++j) {
        if (v[j] > m1) { m2 = m1; m1 = v[j]; }
        else if (v[j] > m2) { m2 = v[j]; }
    }
#pragma unroll
    for (int d = 1; d <= 4; d <<= 1) {
        const double o1 = __shfl_xor(m1, d);
        const double o2 = __shfl_xor(m2, d);
        if (o1 > m1) { m2 = fmax(m1, o2); m1 = o1; }
        else         { m2 = fmax(m2, o1); }
    }
    const double gsum = m1 + m2;

    double gq[8];
#pragma unroll
    for (int g = 0; g < 8; ++g) gq[g] = __shfl(gsum, g * 8);
    int gm = 0;
#pragma unroll
    for (int rr = 0; rr < 4; ++rr) {
        int best = 0; double bv = -1e300;
#pragma unroll
        for (int g = 0; g < 8; ++g) {
            const bool taken = (gm >> g) & 1;
            if (!taken && gq[g] > bv) { bv = gq[g]; best = g; }
        }
        gm |= (1 << best);
    }

    double cv[4];
    const bool inmask = (gm >> (lane >> 3)) & 1;
#pragma unroll
    for (int j = 0; j < 4; ++j) cv[j] = inmask ? v[j] : 0.0;

    double wsum = 0.0, my_w = 0.0;
    int my_i = 0;
#pragma unroll
    for (int rr = 0; rr < 8; ++rr) {
        double bv = cv[0]; int bj = 0;
#pragma unroll
        for (int j = 1; j < 4; ++j)
            if (cv[j] > bv) { bv = cv[j]; bj = j; }
        int bi = 4 * lane + bj;
        double braw = (bj == 0) ? raw[0] : (bj == 1) ? raw[1] : (bj == 2) ? raw[2] : raw[3];
#pragma unroll
        for (int d = 1; d < 64; d <<= 1) {
            const double ov  = __shfl_xor(bv, d);
            const int    oi  = __shfl_xor(bi, d);
            const double orw = __shfl_xor(braw, d);
            if (ov > bv || (ov == bv && oi < bi)) { bv = ov; bi = oi; braw = orw; }
        }
        wsum += braw;
        if (lane == rr) { my_i = bi; my_w = braw; }
        if ((bi >> 2) == lane) cv[bi & 3] = -1e300;
    }

    const double scale = 2.5 / (wsum + 1e-20);
    if (lane < 8) {
        out_idx[(size_t)t * 8 + lane] = (float)my_i;
        out_w [(size_t)t * 8 + lane] = (float)(my_w * scale);
    }
}

extern "C" void kernel_launch(void* const* d_in, const int* in_sizes, int n_in,
                              void* d_out, int out_size, void* d_ws, size_t ws_size,
                              hipStream_t stream)
{
    const float* x    = (const float*)d_in[0];
    const float* w    = (const float*)d_in[1];
    const float* bias = (const float*)d_in[2];
    float* out = (float*)d_out;

    // ws layout (15.01 MiB total; <= proven 16 MiB):
    char* ws = (char*)d_ws;
    float*  logits = (float*)ws;                       // 8192*256*4 = 8,388,608
    double* resc   = (double*)ws;                      // ALIAS: logits dead after route_flag
    u16*    wh     = (u16*)(ws + 8388608);             // 3,670,016
    u16*    wl     = (u16*)(ws + 12058624);            // 3,670,016
    int*    cnt    = (int*)(ws + 15728640);
    int*    list   = (int*)(ws + 15728704);            // 2048*4

    zero_cnt<<<1, 64, 0, stream>>>(cnt);
    wsplit<<<(N_EXP * HID) / (256 * 8), 256, 0, stream>>>(w, wh, wl);
    gemm_bf16split<<<T_TOK / 32, 512, 0, stream>>>(x, wh, wl, logits);
    route_flag<<<T_TOK / 4, 256, 0, stream>>>(logits, bias, out, out + (size_t)T_TOK * 8, cnt, list);
    rescue_gemm64<<<dim3(N_EXP / 32, RESCUE_CAP / 64), 256, 0, stream>>>(x, w, cnt, list, resc);
    rescue_route<<<RESCUE_CAP / 4, 256, 0, stream>>>(resc, bias, cnt, list, out, out + (size_t)T_TOK * 8);
}

// Round 8
// 680.755 us; speedup vs baseline: 2.0144x; 1.1666x over previous
//
#include <hip/hip_runtime.h>
#include <cmath>

#define T_TOK 8192
#define N_EXP 256
#define HID   7168
#define RESCUE_CAP 2048
#define MTAU 4e-5     // expert-chain margin threshold (score space), ~3x the 5-sigma bf16-split error
#define GTAU 1.6e-4   // group-sum margin threshold (= 4*MTAU)

typedef unsigned short u16;
typedef short bf16x8 __attribute__((ext_vector_type(8)));
typedef short s16x4 __attribute__((ext_vector_type(4)));
typedef float f32x4 __attribute__((ext_vector_type(4)));
typedef double f64x4 __attribute__((ext_vector_type(4)));

__device__ __forceinline__ u16 bf16_rtne(float f) {
    unsigned u = __float_as_uint(f);
    u += 0x7FFFu + ((u >> 16) & 1u);
    return (u16)(u >> 16);
}
__device__ __forceinline__ float bf16_f(u16 h) { return __uint_as_float(((unsigned)h) << 16); }

__global__ void zero_cnt(int* cnt) { if (threadIdx.x == 0) *cnt = 0; }

// ---------------------------------------------------------------------------
// K1: split w fp32 -> (wh, wl) bf16 pair. Exact: wl = bf16(w - float(wh)).
// ---------------------------------------------------------------------------
__global__ __launch_bounds__(256)
void wsplit(const float* __restrict__ w, u16* __restrict__ wh, u16* __restrict__ wl)
{
    const size_t base = ((size_t)blockIdx.x * 256 + threadIdx.x) * 8;
    const float4 f0 = *(const float4*)(w + base);
    const float4 f1 = *(const float4*)(w + base + 4);
    const float f[8] = {f0.x, f0.y, f0.z, f0.w, f1.x, f1.y, f1.z, f1.w};
    bf16x8 H, L;
#pragma unroll
    for (int i = 0; i < 8; ++i) {
        const u16 h = bf16_rtne(f[i]);
        H[i] = (short)h;
        L[i] = (short)bf16_rtne(f[i] - bf16_f(h));
    }
    *(bf16x8*)(wh + base) = H;
    *(bf16x8*)(wl + base) = L;
}

// ---------------------------------------------------------------------------
// K2 v8: bf16-split GEMM, re-tiled for occupancy. BM=64 x BN=64, 256 thr
// (4 waves, each 32x32 = 2x2 of 16x16x32), grid (4,128)=512 blocks = 2/CU
// (r7 was 1/CU -> latency-bound, MfmaUtil 10%). hi*hi+hi*lo+lo*hi passes.
// C/D decoded by on-device probes; A/B maps HW-proven by r7's pass.
// ---------------------------------------------------------------------------
#define GS 40   // LDS row stride in u16 (80 B): row start banks walk 8 positions
__global__ __launch_bounds__(256, 2)
void gemm_bf16split_v8(const float* __restrict__ x, const u16* __restrict__ wh,
                       const u16* __restrict__ wl, float* __restrict__ logits)
{
    __shared__ u16 xh[64][GS], xl[64][GS], wsh_s[64][GS], wsl_s[64][GS];
    const int tid = threadIdx.x;
    const int wave = tid >> 6, lane = tid & 63;
    const int e0 = blockIdx.x * 64;
    const int t0 = blockIdx.y * 64;
    const int la = lane & 15, q8 = (lane >> 4) * 8;

    // calibration probes: decode C/D reg->(row,col) on-device
    bf16x8 pidx = (bf16x8)(short)0, pone = (bf16x8)(short)0;
    if ((lane >> 4) == 0) {
        pidx[0] = (short)bf16_rtne((float)la);
        pone[0] = (short)0x3F80;
    }
    f32x4 pr = __builtin_amdgcn_mfma_f32_16x16x32_bf16(pidx, pone, (f32x4)(0.f), 0, 0, 0);
    f32x4 pc = __builtin_amdgcn_mfma_f32_16x16x32_bf16(pone, pidx, (f32x4)(0.f), 0, 0, 0);
    int rrow[4], rcol[4];
#pragma unroll
    for (int i = 0; i < 4; ++i) {
        rrow[i] = (int)(pr[i] + 0.5f);
        rcol[i] = (int)(pc[i] + 0.5f);
    }

    // staging: x 64 rows x 8 float4 -> 2 float4/thread (chunks c, c+4)
    //          w 64 rows x 4 int4 (32 u16) -> 1 int4/thread per array
    const int sr = tid >> 2;   // 0..63
    const int c4 = tid & 3;
    const float* xp  = x  + (size_t)(t0 + sr) * HID + c4 * 4;
    const u16*   whp = wh + (size_t)(e0 + sr) * HID + c4 * 8;
    const u16*   wlp = wl + (size_t)(e0 + sr) * HID + c4 * 8;

    f32x4 acc[2][2];
#pragma unroll
    for (int i = 0; i < 2; ++i)
#pragma unroll
        for (int j = 0; j < 2; ++j) acc[i][j] = (f32x4)(0.f);

    float4 xv0 = *(const float4*)xp;
    float4 xv1 = *(const float4*)(xp + 16);
    int4 wa = *(const int4*)whp;
    int4 wb = *(const int4*)wlp;

    const int m0 = (wave >> 1) * 32;
    const int n0 = (wave & 1) * 32;

    for (int k0 = 0; k0 < HID; k0 += 32) {
        __syncthreads();
        {   // x: fp32 -> (hi,lo) bf16, packed b64 stores
            const float f0[4] = {xv0.x, xv0.y, xv0.z, xv0.w};
            const float f1[4] = {xv1.x, xv1.y, xv1.z, xv1.w};
            s16x4 H0, L0, H1, L1;
#pragma unroll
            for (int j = 0; j < 4; ++j) {
                const u16 h0 = bf16_rtne(f0[j]);
                H0[j] = (short)h0; L0[j] = (short)bf16_rtne(f0[j] - bf16_f(h0));
                const u16 h1 = bf16_rtne(f1[j]);
                H1[j] = (short)h1; L1[j] = (short)bf16_rtne(f1[j] - bf16_f(h1));
            }
            *(s16x4*)&xh[sr][4 * c4]      = H0;
            *(s16x4*)&xl[sr][4 * c4]      = L0;
            *(s16x4*)&xh[sr][4 * c4 + 16] = H1;
            *(s16x4*)&xl[sr][4 * c4 + 16] = L1;
            *(int4*)&wsh_s[sr][8 * c4] = wa;
            *(int4*)&wsl_s[sr][8 * c4] = wb;
        }
        __syncthreads();
        if (k0 + 32 < HID) {   // register prefetch overlaps MFMA block
            xv0 = *(const float4*)(xp + k0 + 32);
            xv1 = *(const float4*)(xp + k0 + 48);
            wa  = *(const int4*)(whp + k0 + 32);
            wb  = *(const int4*)(wlp + k0 + 32);
        }
        bf16x8 Ah[2], Al[2], Bh[2], Bl[2];
#pragma unroll
        for (int mi = 0; mi < 2; ++mi) {
            Ah[mi] = *(const bf16x8*)&xh[m0 + 16 * mi + la][q8];
            Al[mi] = *(const bf16x8*)&xl[m0 + 16 * mi + la][q8];
        }
#pragma unroll
        for (int ni = 0; ni < 2; ++ni) {
            Bh[ni] = *(const bf16x8*)&wsh_s[n0 + 16 * ni + la][q8];
            Bl[ni] = *(const bf16x8*)&wsl_s[n0 + 16 * ni + la][q8];
        }
#pragma unroll
        for (int mi = 0; mi < 2; ++mi)
#pragma unroll
            for (int ni = 0; ni < 2; ++ni) {
                acc[mi][ni] = __builtin_amdgcn_mfma_f32_16x16x32_bf16(Ah[mi], Bh[ni], acc[mi][ni], 0, 0, 0);
                acc[mi][ni] = __builtin_amdgcn_mfma_f32_16x16x32_bf16(Ah[mi], Bl[ni], acc[mi][ni], 0, 0, 0);
                acc[mi][ni] = __builtin_amdgcn_mfma_f32_16x16x32_bf16(Al[mi], Bh[ni], acc[mi][ni], 0, 0, 0);
            }
    }

#pragma unroll
    for (int mi = 0; mi < 2; ++mi)
#pragma unroll
        for (int ni = 0; ni < 2; ++ni)
#pragma unroll
            for (int i = 0; i < 4; ++i)
                logits[(size_t)(t0 + m0 + 16 * mi + rrow[i]) * N_EXP + e0 + n0 + 16 * ni + rcol[i]] = acc[mi][ni][i];
}

// ---------------------------------------------------------------------------
// K3: routing + margin flags (verbatim r7-proven).
// ---------------------------------------------------------------------------
__global__ __launch_bounds__(256)
void route_flag(const float* __restrict__ logits, const float* __restrict__ bias,
                float* __restrict__ out_idx, float* __restrict__ out_w,
                int* __restrict__ cnt, int* __restrict__ list)
{
    const int wave = threadIdx.x >> 6;
    const int lane = threadIdx.x & 63;
    const int t = blockIdx.x * 4 + wave;

    const float4 lg = *(const float4*)(logits + (size_t)t * N_EXP + 4 * lane);
    const float4 bf = *(const float4*)(bias + 4 * lane);
    const float lgv[4] = {lg.x, lg.y, lg.z, lg.w};
    const float bfv[4] = {bf.x, bf.y, bf.z, bf.w};
    double raw[4], v[4];
#pragma unroll
    for (int j = 0; j < 4; ++j) {
        raw[j] = 1.0 / (1.0 + exp(-(double)lgv[j]));
        v[j] = raw[j] + (double)bfv[j];
    }

    double m1 = -1e300, m2 = -1e300;
#pragma unroll
    for (int j = 0; j < 4; ++j) {
        if (v[j] > m1) { m2 = m1; m1 = v[j]; }
        else if (v[j] > m2) { m2 = v[j]; }
    }
#pragma unroll
    for (int d = 1; d <= 4; d <<= 1) {
        const double o1 = __shfl_xor(m1, d);
        const double o2 = __shfl_xor(m2, d);
        if (o1 > m1) { m2 = fmax(m1, o2); m1 = o1; }
        else         { m2 = fmax(m2, o1); }
    }
    const double gsum = m1 + m2;

    double gq[8];
#pragma unroll
    for (int g = 0; g < 8; ++g) gq[g] = __shfl(gsum, g * 8);
    int gm = 0;
    double g4v = -1e300, gmargin = 1e300;
#pragma unroll
    for (int rr = 0; rr < 5; ++rr) {
        int best = 0; double bv = -1e300;
#pragma unroll
        for (int g = 0; g < 8; ++g) {
            const bool taken = (gm >> g) & 1;
            if (!taken && gq[g] > bv) { bv = gq[g]; best = g; }
        }
        if (rr < 4) { gm |= (1 << best); g4v = bv; }
        else gmargin = g4v - bv;
    }

    double cv[4];
    const bool inmask = (gm >> (lane >> 3)) & 1;
#pragma unroll
    for (int j = 0; j < 4; ++j) cv[j] = inmask ? v[j] : 0.0;

    double wsum = 0.0, my_w = 0.0, prev = 0.0, mmin = 1e300;
    int my_i = 0;
#pragma unroll
    for (int rr = 0; rr < 9; ++rr) {
        double bv = cv[0]; int bj = 0;
#pragma unroll
        for (int j = 1; j < 4; ++j)
            if (cv[j] > bv) { bv = cv[j]; bj = j; }
        int bi = 4 * lane + bj;
        double braw = (bj == 0) ? raw[0] : (bj == 1) ? raw[1] : (bj == 2) ? raw[2] : raw[3];
#pragma unroll
        for (int d = 1; d < 64; d <<= 1) {
            const double ov  = __shfl_xor(bv, d);
            const int    oi  = __shfl_xor(bi, d);
            const double orw = __shfl_xor(braw, d);
            if (ov > bv || (ov == bv && oi < bi)) { bv = ov; bi = oi; braw = orw; }
        }
        if (rr > 0) mmin = fmin(mmin, prev - bv);
        prev = bv;
        if (rr < 8) {
            wsum += braw;
            if (lane == rr) { my_i = bi; my_w = braw; }
            if ((bi >> 2) == lane) cv[bi & 3] = -1e300;
        }
    }

    const double scale = 2.5 / (wsum + 1e-20);
    if (lane < 8) {
        out_idx[(size_t)t * 8 + lane] = (float)my_i;
        out_w [(size_t)t * 8 + lane] = (float)(my_w * scale);
    }
    const bool flag = (mmin < MTAU) || (gmargin < GTAU);
    if (flag && lane == 0) {
        const int idx = atomicAdd(cnt, 1);
        if (idx < RESCUE_CAP) list[idx] = t;
    }
}

// ---------------------------------------------------------------------------
// K4 v8: fp64 rescue GEMM, 32x32 tiles (grid 8 x 64) for 3x better live-block
// spread. 4 waves each 16x16 (wave&1 -> m, wave>>1 -> n). k-major LDS with
// r6-proven bank pattern; calibrated C/D epilogue.
// ---------------------------------------------------------------------------
__global__ __launch_bounds__(256, 4)
void rescue_gemm64_v8(const float* __restrict__ x, const float* __restrict__ w,
                      const int* __restrict__ cnt, const int* __restrict__ list,
                      double* __restrict__ resc /* [RESCUE_CAP][N_EXP] */)
{
    const int nf = min(*cnt, RESCUE_CAP);
    const int t0 = blockIdx.y * 32;
    if (t0 >= nf) return;

    __shared__ double xs[32][33];
    __shared__ double wsh[32][33];
    const int tid  = threadIdx.x;
    const int wave = tid >> 6;
    const int lane = tid & 63;
    const int e0 = blockIdx.x * 32;
    const int la = lane & 15;
    const int kq = lane >> 4;

    const double p_idx = (kq == 0) ? (double)la : 0.0;
    const double p_one = (kq == 0) ? 1.0 : 0.0;
    f64x4 prow = (f64x4)(0.0), pcol = (f64x4)(0.0);
    prow = __builtin_amdgcn_mfma_f64_16x16x4f64(p_idx, p_one, prow, 0, 0, 0);
    pcol = __builtin_amdgcn_mfma_f64_16x16x4f64(p_one, p_idx, pcol, 0, 0, 0);
    int rrow[4], rcol[4];
#pragma unroll
    for (int i = 0; i < 4; ++i) {
        rrow[i] = (int)(prow[i] + 0.5);
        rcol[i] = (int)(pcol[i] + 0.5);
    }

    const int r = tid >> 3;     // 0..31
    const int q = tid & 7;
    const int tr = list[min(t0 + r, nf - 1)];
    const float* xp = x + (size_t)tr * HID + q * 4;
    const float* wp = w + (size_t)(e0 + r) * HID + q * 4;

    f64x4 acc = (f64x4)(0.0);
    float4 xv = *(const float4*)xp;
    float4 wv = *(const float4*)wp;
    const int m0 = (wave & 1) * 16;
    const int n0 = (wave >> 1) * 16;

    for (int k0 = 0; k0 < HID; k0 += 32) {
        __syncthreads();
        {
            const float a[4] = {xv.x, xv.y, xv.z, xv.w};
            const float b[4] = {wv.x, wv.y, wv.z, wv.w};
#pragma unroll
            for (int j = 0; j < 4; ++j) {
                xs[4 * q + j][r]  = (double)a[j];
                wsh[4 * q + j][r] = (double)b[j];
            }
        }
        __syncthreads();
        if (k0 + 32 < HID) {
            xv = *(const float4*)(xp + k0 + 32);
            wv = *(const float4*)(wp + k0 + 32);
        }
#pragma unroll
        for (int s = 0; s < 8; ++s) {
            const int kk = s * 4 + kq;
            const double a = xs[kk][m0 + la];
            const double b = wsh[kk][n0 + la];
            acc = __builtin_amdgcn_mfma_f64_16x16x4f64(a, b, acc, 0, 0, 0);
        }
    }

#pragma unroll
    for (int i = 0; i < 4; ++i) {
        const size_t lt = t0 + m0 + rrow[i];
        resc[lt * N_EXP + e0 + n0 + rcol[i]] = 1.0 / (1.0 + exp(-acc[i]));
    }
}

// ---------------------------------------------------------------------------
// K5: fp64 rescue routing (verbatim r7-proven).
// ---------------------------------------------------------------------------
__global__ __launch_bounds__(256)
void rescue_route(const double* __restrict__ resc, const float* __restrict__ bias,
                  const int* __restrict__ cnt, const int* __restrict__ list,
                  float* __restrict__ out_idx, float* __restrict__ out_w)
{
    const int nf = min(*cnt, RESCUE_CAP);
    const int wave = threadIdx.x >> 6;
    const int lane = threadIdx.x & 63;
    const int i_tok = blockIdx.x * 4 + wave;
    if (i_tok >= nf) return;
    const int t = list[i_tok];
    const double* srow = resc + (size_t)i_tok * N_EXP;

    const float4 bf = *(const float4*)(bias + lane * 4);
    const float bfv[4] = {bf.x, bf.y, bf.z, bf.w};
    double raw[4], v[4];
#pragma unroll
    for (int j = 0; j < 4; ++j) {
        raw[j] = srow[4 * lane + j];
        v[j] = raw[j] + (double)bfv[j];
    }

    double m1 = -1e300, m2 = -1e300;
#pragma unroll
    for (int j = 0; j < 4; ++j) {
        if (v[j] > m1) { m2 = m1; m1 = v[j]; }
        else if (v[j] > m2) { m2 = v[j]; }
    }
#pragma unroll
    for (int d = 1; d <= 4; d <<= 1) {
        const double o1 = __shfl_xor(m1, d);
        const double o2 = __shfl_xor(m2, d);
        if (o1 > m1) { m2 = fmax(m1, o2); m1 = o1; }
        else         { m2 = fmax(m2, o1); }
    }
    const double gsum = m1 + m2;

    double gq[8];
#pragma unroll
    for (int g = 0; g < 8; ++g) gq[g] = __shfl(gsum, g * 8);
    int gm = 0;
#pragma unroll
    for (int rr = 0; rr < 4; ++rr) {
        int best = 0; double bv = -1e300;
#pragma unroll
        for (int g = 0; g < 8; ++g) {
            const bool taken = (gm >> g) & 1;
            if (!taken && gq[g] > bv) { bv = gq[g]; best = g; }
        }
        gm |= (1 << best);
    }

    double cv[4];
    const bool inmask = (gm >> (lane >> 3)) & 1;
#pragma unroll
    for (int j = 0; j < 4; ++j) cv[j] = inmask ? v[j] : 0.0;

    double wsum = 0.0, my_w = 0.0;
    int my_i = 0;
#pragma unroll
    for (int rr = 0; rr < 8; ++rr) {
        double bv = cv[0]; int bj = 0;
#pragma unroll
        for (int j = 1; j < 4; ++j)
            if (cv[j] > bv) { bv = cv[j]; bj = j; }
        int bi = 4 * lane + bj;
        double braw = (bj == 0) ? raw[0] : (bj == 1) ? raw[1] : (bj == 2) ? raw[2] : raw[3];
#pragma unroll
        for (int d = 1; d < 64; d <<= 1) {
            const double ov  = __shfl_xor(bv, d);
            const int    oi  = __shfl_xor(bi, d);
            const double orw = __shfl_xor(braw, d);
            if (ov > bv || (ov == bv && oi < bi)) { bv = ov; bi = oi; braw = orw; }
        }
        wsum += braw;
        if (lane == rr) { my_i = bi; my_w = braw; }
        if ((bi >> 2) == lane) cv[bi & 3] = -1e300;
    }

    const double scale = 2.5 / (wsum + 1e-20);
    if (lane < 8) {
        out_idx[(size_t)t * 8 + lane] = (float)my_i;
        out_w [(size_t)t * 8 + lane] = (float)(my_w * scale);
    }
}

extern "C" void kernel_launch(void* const* d_in, const int* in_sizes, int n_in,
                              void* d_out, int out_size, void* d_ws, size_t ws_size,
                              hipStream_t stream)
{
    const float* x    = (const float*)d_in[0];
    const float* w    = (const float*)d_in[1];
    const float* bias = (const float*)d_in[2];
    float* out = (float*)d_out;

    char* ws = (char*)d_ws;
    float*  logits = (float*)ws;                       // 8,388,608 B
    double* resc   = (double*)ws;                      // alias: logits dead after route_flag
    u16*    wh     = (u16*)(ws + 8388608);             // 3,670,016 B
    u16*    wl     = (u16*)(ws + 12058624);            // 3,670,016 B
    int*    cnt    = (int*)(ws + 15728640);
    int*    list   = (int*)(ws + 15728704);            // 2048*4

    zero_cnt<<<1, 64, 0, stream>>>(cnt);
    wsplit<<<(N_EXP * HID) / (256 * 8), 256, 0, stream>>>(w, wh, wl);
    gemm_bf16split_v8<<<dim3(N_EXP / 64, T_TOK / 64), 256, 0, stream>>>(x, wh, wl, logits);
    route_flag<<<T_TOK / 4, 256, 0, stream>>>(logits, bias, out, out + (size_t)T_TOK * 8, cnt, list);
    rescue_gemm64_v8<<<dim3(N_EXP / 32, RESCUE_CAP / 32), 256, 0, stream>>>(x, w, cnt, list, resc);
    rescue_route<<<RESCUE_CAP / 4, 256, 0, stream>>>(resc, bias, cnt, list, out, out + (size_t)T_TOK * 8);
}